// Round 28
// baseline (47.258 us; speedup 1.0000x reference)
//
#include <hip/hip_runtime.h>

#define TSD 512      // TS (feature dim)
#define SRC 256
#define TGT 256
#define NB  4        // batch
#define KSCALE 2.885390081777927f       // 2*log2(e): exp2(K*x) == exp(2x)
#define SCALE  9.5367431640625e-07f     // 2^-20: overflow headroom for 4-way product
#define EPSV   1e-20f

typedef __attribute__((ext_vector_type(8))) short short8;
typedef __attribute__((ext_vector_type(4))) float f32x4;

// RNE fp32 -> bf16 (hi), returns truncated-back fp32 (R10-proven)
__device__ __forceinline__ ushort bf16_hi(float x, float& back) {
    unsigned u = __float_as_uint(x);
    unsigned r = (u + 0x7FFFu + ((u >> 16) & 1u)) >> 16;
    back = __uint_as_float(r << 16);
    return (ushort)r;
}

// ---------------------------------------------------------------------------
// Split-bf16 MFMA projection with fused conversion (R21-proven, unchanged).
// ---------------------------------------------------------------------------
__global__ __launch_bounds__(256) void mfma_proj_kernel(
    const float* __restrict__ hid, const float* __restrict__ enc,
    const float* __restrict__ W, const float* __restrict__ bias,
    const float* __restrict__ v,
    float* __restrict__ hpE2, float* __restrict__ epE)
{
    const int z = blockIdx.z;
    const float* __restrict__ X = z ? enc : hid;
    const int wofs = z ? TSD : 0;

    __shared__ __align__(16) ushort Ah[64][72];   // 9.2 KB each
    __shared__ __align__(16) ushort Al[64][72];
    __shared__ __align__(16) ushort Bh[64][72];
    __shared__ __align__(16) ushort Bl[64][72];
    __shared__ float tile[64][68];                // 17.4 KB (C staging)

    const int tid  = threadIdx.x;
    const int lane = tid & 63;
    const int w    = tid >> 6;
    const int wm   = w >> 1, wn = w & 1;
    const int fr   = lane & 15;
    const int koct = (lane >> 4) * 8;

    const int o0 = blockIdx.x * 64;
    const int r0 = blockIdx.y * 64;

    const int srow = tid >> 2;        // 0..63 (staging row)
    const int kb   = (tid & 3) * 16;  // 0,16,32,48

    f32x4 acc00 = {0.f, 0.f, 0.f, 0.f};
    f32x4 acc01 = {0.f, 0.f, 0.f, 0.f};
    f32x4 acc10 = {0.f, 0.f, 0.f, 0.f};
    f32x4 acc11 = {0.f, 0.f, 0.f, 0.f};

    for (int k0 = 0; k0 < TSD; k0 += 64) {
        __syncthreads();
        #pragma unroll
        for (int j = 0; j < 4; ++j) {
            const int kc = kb + 4 * j;
            const float4 a = *reinterpret_cast<const float4*>(
                &X[(size_t)(r0 + srow) * TSD + k0 + kc]);
            const float4 bq = *reinterpret_cast<const float4*>(
                &W[(size_t)(o0 + srow) * (2 * TSD) + wofs + k0 + kc]);
            float bk; ushort4 hi, lo; float d;
            hi.x = bf16_hi(a.x, bk); lo.x = bf16_hi(a.x - bk, d);
            hi.y = bf16_hi(a.y, bk); lo.y = bf16_hi(a.y - bk, d);
            hi.z = bf16_hi(a.z, bk); lo.z = bf16_hi(a.z - bk, d);
            hi.w = bf16_hi(a.w, bk); lo.w = bf16_hi(a.w - bk, d);
            *reinterpret_cast<ushort4*>(&Ah[srow][kc]) = hi;
            *reinterpret_cast<ushort4*>(&Al[srow][kc]) = lo;
            hi.x = bf16_hi(bq.x, bk); lo.x = bf16_hi(bq.x - bk, d);
            hi.y = bf16_hi(bq.y, bk); lo.y = bf16_hi(bq.y - bk, d);
            hi.z = bf16_hi(bq.z, bk); lo.z = bf16_hi(bq.z - bk, d);
            hi.w = bf16_hi(bq.w, bk); lo.w = bf16_hi(bq.w - bk, d);
            *reinterpret_cast<ushort4*>(&Bh[srow][kc]) = hi;
            *reinterpret_cast<ushort4*>(&Bl[srow][kc]) = lo;
        }
        __syncthreads();

        #pragma unroll
        for (int p = 0; p < 3; ++p) {
            const ushort (*Ap)[72] = (p == 2) ? Al : Ah;
            const ushort (*Bp)[72] = (p == 1) ? Bl : Bh;
            #pragma unroll
            for (int ks = 0; ks < 2; ++ks) {
                const int kk = ks * 32 + koct;
                short8 a0 = *reinterpret_cast<const short8*>(&Ap[wm * 32 + fr][kk]);
                short8 a1 = *reinterpret_cast<const short8*>(&Ap[wm * 32 + 16 + fr][kk]);
                short8 b0 = *reinterpret_cast<const short8*>(&Bp[wn * 32 + fr][kk]);
                short8 b1 = *reinterpret_cast<const short8*>(&Bp[wn * 32 + 16 + fr][kk]);
                acc00 = __builtin_amdgcn_mfma_f32_16x16x32_bf16(a0, b0, acc00, 0, 0, 0);
                acc01 = __builtin_amdgcn_mfma_f32_16x16x32_bf16(a0, b1, acc01, 0, 0, 0);
                acc10 = __builtin_amdgcn_mfma_f32_16x16x32_bf16(a1, b0, acc10, 0, 0, 0);
                acc11 = __builtin_amdgcn_mfma_f32_16x16x32_bf16(a1, b1, acc11, 0, 0, 0);
            }
        }
    }

    // scatter C fragments into tile[row][col] (layout verified in R10/m89)
    const int crow = (lane >> 4) * 4;
    const int ccol = lane & 15;
    #pragma unroll
    for (int reg = 0; reg < 4; ++reg) {
        tile[wm * 32 + crow + reg][wn * 32 + ccol]           = acc00[reg];
        tile[wm * 32 + crow + reg][wn * 32 + 16 + ccol]      = acc01[reg];
        tile[wm * 32 + 16 + crow + reg][wn * 32 + ccol]      = acc10[reg];
        tile[wm * 32 + 16 + crow + reg][wn * 32 + 16 + ccol] = acc11[reg];
    }
    __syncthreads();

    if (z) {
        const int bb_ = r0 >> 8;
        const int s0  = (r0 & 255) + (tid & 15) * 4;
        #pragma unroll
        for (int it = 0; it < 4; ++it) {
            const int ol = it * 16 + (tid >> 4);
            const float bj = bias[o0 + ol];
            float4 val;
            val.x = __builtin_amdgcn_exp2f((tile[(tid & 15) * 4 + 0][ol] + bj) * KSCALE);
            val.y = __builtin_amdgcn_exp2f((tile[(tid & 15) * 4 + 1][ol] + bj) * KSCALE);
            val.z = __builtin_amdgcn_exp2f((tile[(tid & 15) * 4 + 2][ol] + bj) * KSCALE);
            val.w = __builtin_amdgcn_exp2f((tile[(tid & 15) * 4 + 3][ol] + bj) * KSCALE);
            *reinterpret_cast<float4*>(&epE[((size_t)bb_ * TSD + o0 + ol) * SRC + s0]) = val;
        }
    } else {
        const int r_l = tid >> 2;
        const int c0  = (tid & 3) * 16;
        #pragma unroll
        for (int j = 0; j < 4; ++j) {
            const int oc = c0 + j * 4;
            float4 q;
            q.x = __builtin_amdgcn_exp2f(tile[r_l][oc + 0] * KSCALE) *
                  (SCALE * __builtin_amdgcn_rcpf(fmaxf(v[o0 + oc + 0], EPSV)));
            q.y = __builtin_amdgcn_exp2f(tile[r_l][oc + 1] * KSCALE) *
                  (SCALE * __builtin_amdgcn_rcpf(fmaxf(v[o0 + oc + 1], EPSV)));
            q.z = __builtin_amdgcn_exp2f(tile[r_l][oc + 2] * KSCALE) *
                  (SCALE * __builtin_amdgcn_rcpf(fmaxf(v[o0 + oc + 2], EPSV)));
            q.w = __builtin_amdgcn_exp2f(tile[r_l][oc + 3] * KSCALE) *
                  (SCALE * __builtin_amdgcn_rcpf(fmaxf(v[o0 + oc + 3], EPSV)));
            *reinterpret_cast<float4*>(&hpE2[(size_t)(r0 + r_l) * TSD + o0 + oc]) = q;
        }
    }
}

__device__ __forceinline__ float wave_red_sum(float v) {
    #pragma unroll
    for (int off = 1; off < 64; off <<= 1) v += __shfl_xor(v, off, 64);
    return v;
}
__device__ __forceinline__ float wave_red_max(float v) {
    #pragma unroll
    for (int off = 1; off < 64; off <<= 1) v = fmaxf(v, __shfl_xor(v, off, 64));
    return v;
}

// 4 t-rows at one s: w_t = eh_t*ee + iv (one fma each); 4 terms share one rcp
#define GRP4(EH, EE, IV, A0, A1, A2, A3) {                        \
    const float w0_ = fmaf((EH).x, (EE), IV);                     \
    const float w1_ = fmaf((EH).y, (EE), IV);                     \
    const float w2_ = fmaf((EH).z, (EE), IV);                     \
    const float w3_ = fmaf((EH).w, (EE), IV);                     \
    const float p01_ = w0_ * w1_;                                 \
    const float p23_ = w2_ * w3_;                                 \
    const float r_   = __builtin_amdgcn_rcpf(p01_ * p23_);        \
    const float rp01_ = r_ * p01_;                                \
    const float rp23_ = r_ * p23_;                                \
    A0 = fmaf(rp23_, w1_, A0); A1 = fmaf(rp23_, w0_, A1);         \
    A2 = fmaf(rp01_, w3_, A2); A3 = fmaf(rp01_, w2_, A3); }

// ---------------------------------------------------------------------------
// Fused score + softmax + context (R26 structure, one change: score loop
// unroll 4 -> 8 for deeper ee load lookahead / latency coverage).
// Grid (TGT/4, NB), 1024 thr = 16 waves.
// ---------------------------------------------------------------------------
__global__ __launch_bounds__(1024) void attn_fused_kernel(
    const float* __restrict__ hpE2, const float* __restrict__ epE,
    const float* __restrict__ v, const int* __restrict__ mask,
    const float* __restrict__ enc,
    float* __restrict__ ctx_out, float* __restrict__ probs_out)
{
    __shared__ float4 eh4[TSD];         // Eh2s packed by t       (8 KB)
    __shared__ float  ivs[TSD];         // S/v[o]                 (2 KB)
    __shared__ float  accs8[4][8][SRC]; // partials (2-stage); ctx combine alias (32 KB)
    __shared__ float  Plds[4][SRC];     // P sums                 (4 KB)
    __shared__ __align__(16) float Plds4f[SRC][4];  // packed probs (4 KB)
    __shared__ float  redgA[4][4];
    __shared__ float  redgB[4][4];

    const int tid = threadIdx.x;

    // ---- XCD-aware swizzle (R25): each XCD owns one batch, half its tiles ----
    const int L    = blockIdx.x + (int)(gridDim.x) * blockIdx.y;
    const int xcd  = L & 7;
    const int slot = L >> 3;                 // 0..31
    const int b    = xcd >> 1;
    const int t0   = ((xcd & 1) * 32 + slot) * 4;

    // ---- stage Eh2s (4 rows packed per o) + ivs ----
    if (tid < 512) {
        const int row = tid >> 7;            // 0..3
        const int oq  = (tid & 127) * 4;
        const float4 hh = *reinterpret_cast<const float4*>(
            &hpE2[((size_t)(b * TGT + t0 + row)) * TSD + oq]);
        ((float*)&eh4[oq + 0])[row] = hh.x;
        ((float*)&eh4[oq + 1])[row] = hh.y;
        ((float*)&eh4[oq + 2])[row] = hh.z;
        ((float*)&eh4[oq + 3])[row] = hh.w;
    } else {
        const int o = tid - 512;
        ivs[o] = SCALE * __builtin_amdgcn_rcpf(fmaxf(v[o], EPSV));
    }
    __syncthreads();

    // ---- score partials: wave owns o-slice [32w, 32w+32), lane owns 4 s ----
    const int w    = __builtin_amdgcn_readfirstlane(tid >> 6);  // wave 0..15
    const int lane = tid & 63;
    const int obase = w * 32;
    const float* __restrict__ epb =
        epE + (size_t)b * TSD * SRC + (size_t)obase * SRC + 4 * lane;

    float acc[4][4] = {};   // [t][s-sub]
    #pragma unroll 8
    for (int oi = 0; oi < 32; ++oi) {
        const int o = obase + oi;
        const float4 ee = *reinterpret_cast<const float4*>(epb + (size_t)oi * SRC);
        const float4 eh = eh4[o];       // uniform -> ds_read_b128 broadcast
        const float  iv = ivs[o];       // uniform -> ds_read_b32 broadcast
        GRP4(eh, ee.x, iv, acc[0][0], acc[1][0], acc[2][0], acc[3][0])
        GRP4(eh, ee.y, iv, acc[0][1], acc[1][1], acc[2][1], acc[3][1])
        GRP4(eh, ee.z, iv, acc[0][2], acc[1][2], acc[2][2], acc[3][2])
        GRP4(eh, ee.w, iv, acc[0][3], acc[1][3], acc[2][3], acc[3][3])
    }

    // ---- two-stage combine (deterministic, 32 KB) ----
    if (w < 8) {
        #pragma unroll
        for (int t = 0; t < 4; ++t) {
            float4 r4; r4.x = acc[t][0]; r4.y = acc[t][1]; r4.z = acc[t][2]; r4.w = acc[t][3];
            *reinterpret_cast<float4*>(&accs8[t][w][4 * lane]) = r4;
        }
    }
    __syncthreads();
    if (w >= 8) {   // each (t, w-8, s) slot touched by exactly ONE wave: race-free
        const int w8 = w - 8;
        #pragma unroll
        for (int t = 0; t < 4; ++t) {
            float4 cur = *reinterpret_cast<const float4*>(&accs8[t][w8][4 * lane]);
            cur.x += acc[t][0]; cur.y += acc[t][1];
            cur.z += acc[t][2]; cur.w += acc[t][3];
            *reinterpret_cast<float4*>(&accs8[t][w8][4 * lane]) = cur;
        }
    }
    __syncthreads();
    {
        const int t = tid >> 8;          // 0..3
        const int s = tid & 255;
        float Ps = 0.f;
        #pragma unroll
        for (int r = 0; r < 8; ++r) Ps += accs8[t][r][s];
        Plds[t][s] = Ps * SCALE;
    }
    __syncthreads();

    // ---- softmax: group g = tid>>8 handles row t0+g, s = tid&255 ----
    const int g = __builtin_amdgcn_readfirstlane(tid >> 8);
    const int s = tid & 255;
    const int wig = (tid >> 6) & 3;

    float sv = v[s] + v[s + 256];
    {
        float wsv = wave_red_sum(sv);
        if ((tid & 63) == 0) redgA[g][wig] = wsv;
    }
    __syncthreads();
    const float sumv = redgA[g][0] + redgA[g][1] + redgA[g][2] + redgA[g][3];
    const float score = sumv - 2.f * Plds[g][s];

    {
        float wm = wave_red_max(score);
        if ((tid & 63) == 0) redgB[g][wig] = wm;
    }
    __syncthreads();
    const float mx = fmaxf(fmaxf(redgB[g][0], redgB[g][1]), fmaxf(redgB[g][2], redgB[g][3]));
    const float e = __expf(score - mx);
    {
        float ws = wave_red_sum(e);
        if ((tid & 63) == 0) redgA[g][wig] = ws;
    }
    __syncthreads();
    const float sE = redgA[g][0] + redgA[g][1] + redgA[g][2] + redgA[g][3];
    const float mq = (e / sE) * (float)mask[b * SRC + s];
    {
        float ws = wave_red_sum(mq);
        if ((tid & 63) == 0) redgB[g][wig] = ws;
    }
    __syncthreads();
    const float sM = redgB[g][0] + redgB[g][1] + redgB[g][2] + redgB[g][3];
    const float p = mq / (sM + 1e-12f);
    Plds4f[s][g] = p;                      // packed probs (distinct buffer)
    probs_out[((size_t)(b * TGT + t0 + g)) * SRC + s] = p;
    __syncthreads();

    // ---- context: sh2 = tid>>9 owns s-half, d = tid&511; 4 rows per load ----
    const int sh2 = __builtin_amdgcn_readfirstlane(tid >> 9);   // 0..1
    const int d   = tid & 511;
    const float* __restrict__ encb =
        enc + (size_t)b * SRC * TSD + (size_t)(sh2 * 128) * TSD + d;
    float c0 = 0.f, c1 = 0.f, c2 = 0.f, c3 = 0.f;
    #pragma unroll 4
    for (int s2 = 0; s2 < 128; ++s2) {
        const float ev = encb[(size_t)s2 * TSD];
        const float4 pq = *reinterpret_cast<const float4*>(
            &Plds4f[sh2 * 128 + s2][0]);        // uniform b128 broadcast
        c0 = fmaf(pq.x, ev, c0);
        c1 = fmaf(pq.y, ev, c1);
        c2 = fmaf(pq.z, ev, c2);
        c3 = fmaf(pq.w, ev, c3);
    }
    // combine the two s-halves via LDS (aliases accs8, dead since combine)
    float* cpart = (float*)accs8;    // [sh2*4 + row][512]
    cpart[((sh2 * 4 + 0) << 9) | d] = c0;
    cpart[((sh2 * 4 + 1) << 9) | d] = c1;
    cpart[((sh2 * 4 + 2) << 9) | d] = c2;
    cpart[((sh2 * 4 + 3) << 9) | d] = c3;
    __syncthreads();
    {
        const int rg = tid >> 9;    // row pair 0..1
        const float r0 = cpart[((2 * rg) << 9) | d]     + cpart[((4 + 2 * rg) << 9) | d];
        const float r1 = cpart[((2 * rg + 1) << 9) | d] + cpart[((4 + 2 * rg + 1) << 9) | d];
        ctx_out[((size_t)(b * TGT + t0 + 2 * rg)) * TSD + d]     = r0;
        ctx_out[((size_t)(b * TGT + t0 + 2 * rg + 1)) * TSD + d] = r1;
    }
}

extern "C" void kernel_launch(void* const* d_in, const int* in_sizes, int n_in,
                              void* d_out, int out_size, void* d_ws, size_t ws_size,
                              hipStream_t stream) {
    const float* hid  = (const float*)d_in[0];   // (4,256,512)
    const float* enc  = (const float*)d_in[1];   // (4,256,512)
    const int*   mask = (const int*)  d_in[2];   // (4,256)
    const float* W    = (const float*)d_in[3];   // (512,1024)
    const float* bias = (const float*)d_in[4];   // (512,)
    const float* v    = (const float*)d_in[5];   // (512,)

    float* out   = (float*)d_out;
    float* ctx   = out;                       // 4*256*512
    float* probs = out + NB * TGT * TSD;      // 4*256*256

    float* hpE2 = (float*)d_ws;               // 1024*512: S*exp2(K*h)/v    2 MB
    float* epE  = hpE2 + NB * TGT * TSD;      // 4*512*256: exp2(K*(e+b))^T 2 MB

    dim3 pg(TSD / 64, (NB * TGT) / 64, 2);
    mfma_proj_kernel<<<pg, 256, 0, stream>>>(hid, enc, W, bias, v, hpE2, epE);

    dim3 ag(TGT / 4, NB);
    attn_fused_kernel<<<ag, 1024, 0, stream>>>(hpE2, epE, v, mask, enc, ctx, probs);
}

// Round 29
// 44.805 us; speedup vs baseline: 1.0548x; 1.0548x over previous
//
#include <hip/hip_runtime.h>

#define TSD 512      // TS (feature dim)
#define SRC 256
#define TGT 256
#define NB  4        // batch
#define KSCALE 2.885390081777927f       // 2*log2(e): exp2(K*x) == exp(2x)
#define SCALE  9.5367431640625e-07f     // 2^-20: overflow headroom for 4-way product
#define EPSV   1e-20f

typedef __attribute__((ext_vector_type(8))) short short8;
typedef __attribute__((ext_vector_type(4))) float f32x4;

// RNE fp32 -> bf16 (hi), returns truncated-back fp32 (R10-proven)
__device__ __forceinline__ ushort bf16_hi(float x, float& back) {
    unsigned u = __float_as_uint(x);
    unsigned r = (u + 0x7FFFu + ((u >> 16) & 1u)) >> 16;
    back = __uint_as_float(r << 16);
    return (ushort)r;
}

// ---------------------------------------------------------------------------
// Split-bf16 MFMA projection with fused conversion (R21-proven, unchanged).
// ---------------------------------------------------------------------------
__global__ __launch_bounds__(256) void mfma_proj_kernel(
    const float* __restrict__ hid, const float* __restrict__ enc,
    const float* __restrict__ W, const float* __restrict__ bias,
    const float* __restrict__ v,
    float* __restrict__ hpE2, float* __restrict__ epE)
{
    const int z = blockIdx.z;
    const float* __restrict__ X = z ? enc : hid;
    const int wofs = z ? TSD : 0;

    __shared__ __align__(16) ushort Ah[64][72];   // 9.2 KB each
    __shared__ __align__(16) ushort Al[64][72];
    __shared__ __align__(16) ushort Bh[64][72];
    __shared__ __align__(16) ushort Bl[64][72];
    __shared__ float tile[64][68];                // 17.4 KB (C staging)

    const int tid  = threadIdx.x;
    const int lane = tid & 63;
    const int w    = tid >> 6;
    const int wm   = w >> 1, wn = w & 1;
    const int fr   = lane & 15;
    const int koct = (lane >> 4) * 8;

    const int o0 = blockIdx.x * 64;
    const int r0 = blockIdx.y * 64;

    const int srow = tid >> 2;        // 0..63 (staging row)
    const int kb   = (tid & 3) * 16;  // 0,16,32,48

    f32x4 acc00 = {0.f, 0.f, 0.f, 0.f};
    f32x4 acc01 = {0.f, 0.f, 0.f, 0.f};
    f32x4 acc10 = {0.f, 0.f, 0.f, 0.f};
    f32x4 acc11 = {0.f, 0.f, 0.f, 0.f};

    for (int k0 = 0; k0 < TSD; k0 += 64) {
        __syncthreads();
        #pragma unroll
        for (int j = 0; j < 4; ++j) {
            const int kc = kb + 4 * j;
            const float4 a = *reinterpret_cast<const float4*>(
                &X[(size_t)(r0 + srow) * TSD + k0 + kc]);
            const float4 bq = *reinterpret_cast<const float4*>(
                &W[(size_t)(o0 + srow) * (2 * TSD) + wofs + k0 + kc]);
            float bk; ushort4 hi, lo; float d;
            hi.x = bf16_hi(a.x, bk); lo.x = bf16_hi(a.x - bk, d);
            hi.y = bf16_hi(a.y, bk); lo.y = bf16_hi(a.y - bk, d);
            hi.z = bf16_hi(a.z, bk); lo.z = bf16_hi(a.z - bk, d);
            hi.w = bf16_hi(a.w, bk); lo.w = bf16_hi(a.w - bk, d);
            *reinterpret_cast<ushort4*>(&Ah[srow][kc]) = hi;
            *reinterpret_cast<ushort4*>(&Al[srow][kc]) = lo;
            hi.x = bf16_hi(bq.x, bk); lo.x = bf16_hi(bq.x - bk, d);
            hi.y = bf16_hi(bq.y, bk); lo.y = bf16_hi(bq.y - bk, d);
            hi.z = bf16_hi(bq.z, bk); lo.z = bf16_hi(bq.z - bk, d);
            hi.w = bf16_hi(bq.w, bk); lo.w = bf16_hi(bq.w - bk, d);
            *reinterpret_cast<ushort4*>(&Bh[srow][kc]) = hi;
            *reinterpret_cast<ushort4*>(&Bl[srow][kc]) = lo;
        }
        __syncthreads();

        #pragma unroll
        for (int p = 0; p < 3; ++p) {
            const ushort (*Ap)[72] = (p == 2) ? Al : Ah;
            const ushort (*Bp)[72] = (p == 1) ? Bl : Bh;
            #pragma unroll
            for (int ks = 0; ks < 2; ++ks) {
                const int kk = ks * 32 + koct;
                short8 a0 = *reinterpret_cast<const short8*>(&Ap[wm * 32 + fr][kk]);
                short8 a1 = *reinterpret_cast<const short8*>(&Ap[wm * 32 + 16 + fr][kk]);
                short8 b0 = *reinterpret_cast<const short8*>(&Bp[wn * 32 + fr][kk]);
                short8 b1 = *reinterpret_cast<const short8*>(&Bp[wn * 32 + 16 + fr][kk]);
                acc00 = __builtin_amdgcn_mfma_f32_16x16x32_bf16(a0, b0, acc00, 0, 0, 0);
                acc01 = __builtin_amdgcn_mfma_f32_16x16x32_bf16(a0, b1, acc01, 0, 0, 0);
                acc10 = __builtin_amdgcn_mfma_f32_16x16x32_bf16(a1, b0, acc10, 0, 0, 0);
                acc11 = __builtin_amdgcn_mfma_f32_16x16x32_bf16(a1, b1, acc11, 0, 0, 0);
            }
        }
    }

    // scatter C fragments into tile[row][col] (layout verified in R10/m89)
    const int crow = (lane >> 4) * 4;
    const int ccol = lane & 15;
    #pragma unroll
    for (int reg = 0; reg < 4; ++reg) {
        tile[wm * 32 + crow + reg][wn * 32 + ccol]           = acc00[reg];
        tile[wm * 32 + crow + reg][wn * 32 + 16 + ccol]      = acc01[reg];
        tile[wm * 32 + 16 + crow + reg][wn * 32 + ccol]      = acc10[reg];
        tile[wm * 32 + 16 + crow + reg][wn * 32 + 16 + ccol] = acc11[reg];
    }
    __syncthreads();

    if (z) {
        const int bb_ = r0 >> 8;
        const int s0  = (r0 & 255) + (tid & 15) * 4;
        #pragma unroll
        for (int it = 0; it < 4; ++it) {
            const int ol = it * 16 + (tid >> 4);
            const float bj = bias[o0 + ol];
            float4 val;
            val.x = __builtin_amdgcn_exp2f((tile[(tid & 15) * 4 + 0][ol] + bj) * KSCALE);
            val.y = __builtin_amdgcn_exp2f((tile[(tid & 15) * 4 + 1][ol] + bj) * KSCALE);
            val.z = __builtin_amdgcn_exp2f((tile[(tid & 15) * 4 + 2][ol] + bj) * KSCALE);
            val.w = __builtin_amdgcn_exp2f((tile[(tid & 15) * 4 + 3][ol] + bj) * KSCALE);
            *reinterpret_cast<float4*>(&epE[((size_t)bb_ * TSD + o0 + ol) * SRC + s0]) = val;
        }
    } else {
        const int r_l = tid >> 2;
        const int c0  = (tid & 3) * 16;
        #pragma unroll
        for (int j = 0; j < 4; ++j) {
            const int oc = c0 + j * 4;
            float4 q;
            q.x = __builtin_amdgcn_exp2f(tile[r_l][oc + 0] * KSCALE) *
                  (SCALE * __builtin_amdgcn_rcpf(fmaxf(v[o0 + oc + 0], EPSV)));
            q.y = __builtin_amdgcn_exp2f(tile[r_l][oc + 1] * KSCALE) *
                  (SCALE * __builtin_amdgcn_rcpf(fmaxf(v[o0 + oc + 1], EPSV)));
            q.z = __builtin_amdgcn_exp2f(tile[r_l][oc + 2] * KSCALE) *
                  (SCALE * __builtin_amdgcn_rcpf(fmaxf(v[o0 + oc + 2], EPSV)));
            q.w = __builtin_amdgcn_exp2f(tile[r_l][oc + 3] * KSCALE) *
                  (SCALE * __builtin_amdgcn_rcpf(fmaxf(v[o0 + oc + 3], EPSV)));
            *reinterpret_cast<float4*>(&hpE2[(size_t)(r0 + r_l) * TSD + o0 + oc]) = q;
        }
    }
}

__device__ __forceinline__ float wave_red_sum(float v) {
    #pragma unroll
    for (int off = 1; off < 64; off <<= 1) v += __shfl_xor(v, off, 64);
    return v;
}
__device__ __forceinline__ float wave_red_max(float v) {
    #pragma unroll
    for (int off = 1; off < 64; off <<= 1) v = fmaxf(v, __shfl_xor(v, off, 64));
    return v;
}

// 4 t-rows at one s: w_t = eh_t*ee + iv (one fma each); 4 terms share one rcp
#define GRP4(EH, EE, IV, A0, A1, A2, A3) {                        \
    const float w0_ = fmaf((EH).x, (EE), IV);                     \
    const float w1_ = fmaf((EH).y, (EE), IV);                     \
    const float w2_ = fmaf((EH).z, (EE), IV);                     \
    const float w3_ = fmaf((EH).w, (EE), IV);                     \
    const float p01_ = w0_ * w1_;                                 \
    const float p23_ = w2_ * w3_;                                 \
    const float r_   = __builtin_amdgcn_rcpf(p01_ * p23_);        \
    const float rp01_ = r_ * p01_;                                \
    const float rp23_ = r_ * p23_;                                \
    A0 = fmaf(rp23_, w1_, A0); A1 = fmaf(rp23_, w0_, A1);         \
    A2 = fmaf(rp01_, w3_, A2); A3 = fmaf(rp01_, w2_, A3); }

// ---------------------------------------------------------------------------
// Fused score + softmax + context (R26 exact: float4 ee, unroll 4, two-stage
// 32 KB combine, packed-probs ctx, XCD swizzle). Session-best configuration.
// Grid (TGT/4, NB), 1024 thr = 16 waves.
// ---------------------------------------------------------------------------
__global__ __launch_bounds__(1024) void attn_fused_kernel(
    const float* __restrict__ hpE2, const float* __restrict__ epE,
    const float* __restrict__ v, const int* __restrict__ mask,
    const float* __restrict__ enc,
    float* __restrict__ ctx_out, float* __restrict__ probs_out)
{
    __shared__ float4 eh4[TSD];         // Eh2s packed by t       (8 KB)
    __shared__ float  ivs[TSD];         // S/v[o]                 (2 KB)
    __shared__ float  accs8[4][8][SRC]; // partials (2-stage); ctx combine alias (32 KB)
    __shared__ float  Plds[4][SRC];     // P sums                 (4 KB)
    __shared__ __align__(16) float Plds4f[SRC][4];  // packed probs (4 KB)
    __shared__ float  redgA[4][4];
    __shared__ float  redgB[4][4];

    const int tid = threadIdx.x;

    // ---- XCD-aware swizzle (R25): each XCD owns one batch, half its tiles ----
    const int L    = blockIdx.x + (int)(gridDim.x) * blockIdx.y;
    const int xcd  = L & 7;
    const int slot = L >> 3;                 // 0..31
    const int b    = xcd >> 1;
    const int t0   = ((xcd & 1) * 32 + slot) * 4;

    // ---- stage Eh2s (4 rows packed per o) + ivs ----
    if (tid < 512) {
        const int row = tid >> 7;            // 0..3
        const int oq  = (tid & 127) * 4;
        const float4 hh = *reinterpret_cast<const float4*>(
            &hpE2[((size_t)(b * TGT + t0 + row)) * TSD + oq]);
        ((float*)&eh4[oq + 0])[row] = hh.x;
        ((float*)&eh4[oq + 1])[row] = hh.y;
        ((float*)&eh4[oq + 2])[row] = hh.z;
        ((float*)&eh4[oq + 3])[row] = hh.w;
    } else {
        const int o = tid - 512;
        ivs[o] = SCALE * __builtin_amdgcn_rcpf(fmaxf(v[o], EPSV));
    }
    __syncthreads();

    // ---- score partials: wave owns o-slice [32w, 32w+32), lane owns 4 s ----
    const int w    = __builtin_amdgcn_readfirstlane(tid >> 6);  // wave 0..15
    const int lane = tid & 63;
    const int obase = w * 32;
    const float* __restrict__ epb =
        epE + (size_t)b * TSD * SRC + (size_t)obase * SRC + 4 * lane;

    float acc[4][4] = {};   // [t][s-sub]
    #pragma unroll 4
    for (int oi = 0; oi < 32; ++oi) {
        const int o = obase + oi;
        const float4 ee = *reinterpret_cast<const float4*>(epb + (size_t)oi * SRC);
        const float4 eh = eh4[o];       // uniform -> ds_read_b128 broadcast
        const float  iv = ivs[o];       // uniform -> ds_read_b32 broadcast
        GRP4(eh, ee.x, iv, acc[0][0], acc[1][0], acc[2][0], acc[3][0])
        GRP4(eh, ee.y, iv, acc[0][1], acc[1][1], acc[2][1], acc[3][1])
        GRP4(eh, ee.z, iv, acc[0][2], acc[1][2], acc[2][2], acc[3][2])
        GRP4(eh, ee.w, iv, acc[0][3], acc[1][3], acc[2][3], acc[3][3])
    }

    // ---- two-stage combine (deterministic, 32 KB) ----
    if (w < 8) {
        #pragma unroll
        for (int t = 0; t < 4; ++t) {
            float4 r4; r4.x = acc[t][0]; r4.y = acc[t][1]; r4.z = acc[t][2]; r4.w = acc[t][3];
            *reinterpret_cast<float4*>(&accs8[t][w][4 * lane]) = r4;
        }
    }
    __syncthreads();
    if (w >= 8) {   // each (t, w-8, s) slot touched by exactly ONE wave: race-free
        const int w8 = w - 8;
        #pragma unroll
        for (int t = 0; t < 4; ++t) {
            float4 cur = *reinterpret_cast<const float4*>(&accs8[t][w8][4 * lane]);
            cur.x += acc[t][0]; cur.y += acc[t][1];
            cur.z += acc[t][2]; cur.w += acc[t][3];
            *reinterpret_cast<float4*>(&accs8[t][w8][4 * lane]) = cur;
        }
    }
    __syncthreads();
    {
        const int t = tid >> 8;          // 0..3
        const int s = tid & 255;
        float Ps = 0.f;
        #pragma unroll
        for (int r = 0; r < 8; ++r) Ps += accs8[t][r][s];
        Plds[t][s] = Ps * SCALE;
    }
    __syncthreads();

    // ---- softmax: group g = tid>>8 handles row t0+g, s = tid&255 ----
    const int g = __builtin_amdgcn_readfirstlane(tid >> 8);
    const int s = tid & 255;
    const int wig = (tid >> 6) & 3;

    float sv = v[s] + v[s + 256];
    {
        float wsv = wave_red_sum(sv);
        if ((tid & 63) == 0) redgA[g][wig] = wsv;
    }
    __syncthreads();
    const float sumv = redgA[g][0] + redgA[g][1] + redgA[g][2] + redgA[g][3];
    const float score = sumv - 2.f * Plds[g][s];

    {
        float wm = wave_red_max(score);
        if ((tid & 63) == 0) redgB[g][wig] = wm;
    }
    __syncthreads();
    const float mx = fmaxf(fmaxf(redgB[g][0], redgB[g][1]), fmaxf(redgB[g][2], redgB[g][3]));
    const float e = __expf(score - mx);
    {
        float ws = wave_red_sum(e);
        if ((tid & 63) == 0) redgA[g][wig] = ws;
    }
    __syncthreads();
    const float sE = redgA[g][0] + redgA[g][1] + redgA[g][2] + redgA[g][3];
    const float mq = (e / sE) * (float)mask[b * SRC + s];
    {
        float ws = wave_red_sum(mq);
        if ((tid & 63) == 0) redgB[g][wig] = ws;
    }
    __syncthreads();
    const float sM = redgB[g][0] + redgB[g][1] + redgB[g][2] + redgB[g][3];
    const float p = mq / (sM + 1e-12f);
    Plds4f[s][g] = p;                      // packed probs (distinct buffer)
    probs_out[((size_t)(b * TGT + t0 + g)) * SRC + s] = p;
    __syncthreads();

    // ---- context: sh2 = tid>>9 owns s-half, d = tid&511; 4 rows per load ----
    const int sh2 = __builtin_amdgcn_readfirstlane(tid >> 9);   // 0..1
    const int d   = tid & 511;
    const float* __restrict__ encb =
        enc + (size_t)b * SRC * TSD + (size_t)(sh2 * 128) * TSD + d;
    float c0 = 0.f, c1 = 0.f, c2 = 0.f, c3 = 0.f;
    #pragma unroll 4
    for (int s2 = 0; s2 < 128; ++s2) {
        const float ev = encb[(size_t)s2 * TSD];
        const float4 pq = *reinterpret_cast<const float4*>(
            &Plds4f[sh2 * 128 + s2][0]);        // uniform b128 broadcast
        c0 = fmaf(pq.x, ev, c0);
        c1 = fmaf(pq.y, ev, c1);
        c2 = fmaf(pq.z, ev, c2);
        c3 = fmaf(pq.w, ev, c3);
    }
    // combine the two s-halves via LDS (aliases accs8, dead since combine)
    float* cpart = (float*)accs8;    // [sh2*4 + row][512]
    cpart[((sh2 * 4 + 0) << 9) | d] = c0;
    cpart[((sh2 * 4 + 1) << 9) | d] = c1;
    cpart[((sh2 * 4 + 2) << 9) | d] = c2;
    cpart[((sh2 * 4 + 3) << 9) | d] = c3;
    __syncthreads();
    {
        const int rg = tid >> 9;    // row pair 0..1
        const float r0 = cpart[((2 * rg) << 9) | d]     + cpart[((4 + 2 * rg) << 9) | d];
        const float r1 = cpart[((2 * rg + 1) << 9) | d] + cpart[((4 + 2 * rg + 1) << 9) | d];
        ctx_out[((size_t)(b * TGT + t0 + 2 * rg)) * TSD + d]     = r0;
        ctx_out[((size_t)(b * TGT + t0 + 2 * rg + 1)) * TSD + d] = r1;
    }
}

extern "C" void kernel_launch(void* const* d_in, const int* in_sizes, int n_in,
                              void* d_out, int out_size, void* d_ws, size_t ws_size,
                              hipStream_t stream) {
    const float* hid  = (const float*)d_in[0];   // (4,256,512)
    const float* enc  = (const float*)d_in[1];   // (4,256,512)
    const int*   mask = (const int*)  d_in[2];   // (4,256)
    const float* W    = (const float*)d_in[3];   // (512,1024)
    const float* bias = (const float*)d_in[4];   // (512,)
    const float* v    = (const float*)d_in[5];   // (512,)

    float* out   = (float*)d_out;
    float* ctx   = out;                       // 4*256*512
    float* probs = out + NB * TGT * TSD;      // 4*256*256

    float* hpE2 = (float*)d_ws;               // 1024*512: S*exp2(K*h)/v    2 MB
    float* epE  = hpE2 + NB * TGT * TSD;      // 4*512*256: exp2(K*(e+b))^T 2 MB

    dim3 pg(TSD / 64, (NB * TGT) / 64, 2);
    mfma_proj_kernel<<<pg, 256, 0, stream>>>(hid, enc, W, bias, v, hpE2, epE);

    dim3 ag(TGT / 4, NB);
    attn_fused_kernel<<<ag, 1024, 0, stream>>>(hpE2, epE, v, mask, enc, ctx, probs);
}